// Round 6
// baseline (609.484 us; speedup 1.0000x reference)
//
#include <hip/hip_runtime.h>
#include <hip/hip_bf16.h>
#include <cstdint>
#include <cstddef>

#define BB 4
#define SS 2048
#define DM 1024
#define INNER 2048
#define CHUNK 64
#define NCHK (SS / CHUNK)  // 32

typedef __attribute__((ext_vector_type(8))) __bf16 bf16x8;
typedef __attribute__((ext_vector_type(4))) float f32x4;
typedef __attribute__((ext_vector_type(8))) unsigned short ushort8;
typedef __attribute__((ext_vector_type(4))) unsigned short ushort4v;

#define GPTR(p) ((const __attribute__((address_space(1))) void*)(p))
#define LPTR(p) ((__attribute__((address_space(3))) void*)(p))

__device__ inline float b2f(unsigned short h) {
  union { unsigned u; float f; } v; v.u = ((unsigned)h) << 16; return v.f;
}
__device__ inline unsigned short f2b(float f) {
  unsigned u = __float_as_uint(f);
  u += 0x7fff + ((u >> 16) & 1);   // round-to-nearest-even
  return (unsigned short)(u >> 16);
}
__device__ inline unsigned pack2(float lo, float hi) {
  return (unsigned)f2b(lo) | ((unsigned)f2b(hi) << 16);
}
__device__ inline float sigmoidf_(float x) { return 1.0f / (1.0f + __expf(-x)); }
__device__ inline float tanhf_(float x) { return 2.0f / (1.0f + __expf(-2.0f * x)) - 1.0f; }

// ---------------------------------------------------------------------------
// Transpose + cast: src fp32 [R][C] -> dst bf16 [C][R]
// ---------------------------------------------------------------------------
__global__ void transpose_cast_kernel(const float* __restrict__ src,
                                      unsigned short* __restrict__ dst,
                                      int R, int C) {
  __shared__ float tile[32][33];
  const int c0 = blockIdx.x * 32, r0 = blockIdx.y * 32;
  const int tx = threadIdx.x, ty = threadIdx.y;  // (32,8)
  #pragma unroll
  for (int j = ty; j < 32; j += 8)
    tile[j][tx] = src[(size_t)(r0 + j) * C + c0 + tx];
  __syncthreads();
  #pragma unroll
  for (int j = ty; j < 32; j += 8)
    dst[(size_t)(c0 + j) * R + r0 + tx] = f2b(tile[tx][j]);
}

// ---------------------------------------------------------------------------
// LayerNorm: x fp32 [8192][1024] -> xn bf16
// ---------------------------------------------------------------------------
__global__ __launch_bounds__(256) void layernorm_kernel(
    const float* __restrict__ x, const float* __restrict__ gamma,
    const float* __restrict__ beta, unsigned short* __restrict__ out) {
  const int row = blockIdx.x;
  const int tid = threadIdx.x;
  const float4 v = *(const float4*)(x + (size_t)row * DM + tid * 4);
  float s = v.x + v.y + v.z + v.w;
  #pragma unroll
  for (int o = 32; o >= 1; o >>= 1) s += __shfl_down(s, o, 64);
  __shared__ float red[8];
  const int wid = tid >> 6, lane = tid & 63;
  if (lane == 0) red[wid] = s;
  __syncthreads();
  const float mu = (red[0] + red[1] + red[2] + red[3]) * (1.f / DM);
  const float d0 = v.x - mu, d1 = v.y - mu, d2 = v.z - mu, d3 = v.w - mu;
  float sq = d0 * d0 + d1 * d1 + d2 * d2 + d3 * d3;
  #pragma unroll
  for (int o = 32; o >= 1; o >>= 1) sq += __shfl_down(sq, o, 64);
  if (lane == 0) red[4 + wid] = sq;
  __syncthreads();
  const float var = (red[4] + red[5] + red[6] + red[7]) * (1.f / DM);
  const float rs = rsqrtf(var + 1e-5f);
  const int c0 = tid * 4;
  ushort4v o4;
  o4[0] = f2b(d0 * rs * gamma[c0 + 0] + beta[c0 + 0]);
  o4[1] = f2b(d1 * rs * gamma[c0 + 1] + beta[c0 + 1]);
  o4[2] = f2b(d2 * rs * gamma[c0 + 2] + beta[c0 + 2]);
  o4[3] = f2b(d3 * rs * gamma[c0 + 3] + beta[c0 + 3]);
  *(ushort4v*)(out + (size_t)row * DM + c0) = o4;
}

// ---------------------------------------------------------------------------
// 256x128 GEMM, BK=32, 512 threads (8 waves, 4Mx2N, wave tile 64x64).
// 2-deep LDS double-buffer (48 KB) -> 2 blocks/CU (TLP: independent blocks
// overlap each other's LDS/MFMA/VALU phases). One vmcnt(0)+barrier per K-tile;
// stage of tile t+1 issues right after barrier_t (full tile of latency slack).
// LDS layout (16B units): u = (row>>4)*64 + slot*16 + (row&15)
//   -> ds_read_b128 lane-linear (conflict-free); staging: linear LDS dest,
//      per-lane permuted GLOBAL source.
// Operand-swapped MFMA: acc = mfma(B, A, acc) -> lane holds 4 consecutive C
// columns -> packed stores.
// OUTMODE 0: bf16. OUTMODE 1: fp32 + residual. OUTMODE 2: abc-fused
// (seg0/1 sigmoid, seg2 tanh; segments contiguous [M][2048] bf16 blocks).
// ---------------------------------------------------------------------------
template <int OUTMODE>
__global__ __launch_bounds__(512, 4) void gemm_mn(
    const unsigned short* __restrict__ A, const unsigned short* __restrict__ Bt,
    const float* __restrict__ bias, void* __restrict__ Cout,
    const float* __restrict__ resid, int M, int N, int K, int nbx) {
  __shared__ unsigned short lds[2 * 12288];  // 48 KB: 2 bufs x (A 16KB + B 8KB)
  const int tid = threadIdx.x;
  // bijective XCD swizzle (gridDim.x % 8 == 0)
  const int nwg = gridDim.x;
  const int cpx = nwg >> 3;
  const int bid = blockIdx.x;
  const int swz = (bid & 7) * cpx + (bid >> 3);
  const int m0 = (swz / nbx) * 256, n0 = (swz % nbx) * 128;

  const int l = tid & 63, w = tid >> 6;
  const int wr = w >> 1, wc = w & 1;          // 4 x 2 wave grid
  const int NT = K >> 5;                      // K-tiles of 32

  // fragment bases (elems): lane-linear reads
  const int afo = (wr * 4) * 512 + l * 8;          // + mf*512, mf 0..3
  const int bfo = 8192 + (wc * 4) * 512 + l * 8;   // + nf*512, nf 0..3

  f32x4 acc[4][4];
  #pragma unroll
  for (int i = 0; i < 4; i++)
    #pragma unroll
    for (int j = 0; j < 4; j++) acc[i][j] = (f32x4){0.f, 0.f, 0.f, 0.f};

  // staging source addresses (fixed per thread; only k0 varies)
  const int q0 = tid, q1 = tid + 512;              // A units (1024 total)
  const int row0 = ((q0 >> 6) << 4) | (q0 & 15), slot0 = (q0 >> 4) & 3;
  const int row1 = ((q1 >> 6) << 4) | (q1 & 15), slot1 = (q1 >> 4) & 3;
  const int row2 = row0;                           // B units (512): row < 128
  const unsigned short* Ap0 = A + (size_t)(m0 + row0) * K + slot0 * 8;
  const unsigned short* Ap1 = A + (size_t)(m0 + row1) * K + slot1 * 8;
  const unsigned short* Bp0 = Bt + (size_t)(n0 + row2) * K + slot0 * 8;

  auto stage = [&](int kt, int bufo) {
    int ktw = kt; if (ktw >= NT) ktw -= NT;
    const int k0 = ktw << 5;
    __builtin_amdgcn_global_load_lds(GPTR(Ap0 + k0), LPTR(&lds[bufo + q0 * 8]), 16, 0, 0);
    __builtin_amdgcn_global_load_lds(GPTR(Ap1 + k0), LPTR(&lds[bufo + q1 * 8]), 16, 0, 0);
    __builtin_amdgcn_global_load_lds(GPTR(Bp0 + k0), LPTR(&lds[bufo + 8192 + q0 * 8]), 16, 0, 0);
  };

  stage(0, 0);

  for (int t = 0; t < NT; t++) {
    const int tbo = (t & 1) * 12288;
    // drain this wave's loads for tile t; barrier => all waves' loads done,
    // and all waves finished reading buf[(t-1)&1] = buf[(t+1)&1].
    __builtin_amdgcn_sched_barrier(0);
    asm volatile("s_waitcnt vmcnt(0)" ::: "memory");
    __builtin_amdgcn_sched_barrier(0);
    __builtin_amdgcn_s_barrier();
    __builtin_amdgcn_sched_barrier(0);

    stage(t + 1, ((t + 1) & 1) * 12288);

    bf16x8 af[4], bfv[4];
    #pragma unroll
    for (int mf = 0; mf < 4; mf++)
      af[mf] = *(const bf16x8*)&lds[tbo + afo + mf * 512];
    #pragma unroll
    for (int nf = 0; nf < 4; nf++)
      bfv[nf] = *(const bf16x8*)&lds[tbo + bfo + nf * 512];

    __builtin_amdgcn_s_setprio(1);
    #pragma unroll
    for (int mf = 0; mf < 4; mf++)
      #pragma unroll
      for (int nf = 0; nf < 4; nf++)
        acc[mf][nf] = __builtin_amdgcn_mfma_f32_16x16x32_bf16(bfv[nf], af[mf], acc[mf][nf], 0, 0, 0);
    __builtin_amdgcn_s_setprio(0);
    __builtin_amdgcn_sched_barrier(0);
  }
  // drain stray prefetch before epilogue / endpgm
  asm volatile("s_waitcnt vmcnt(0)" ::: "memory");

  // epilogue: lane holds C[row][colb..colb+3]
  const int rowl = m0 + wr * 64 + (l & 15);
  const int coll = n0 + wc * 64 + (l >> 4) * 4;
  const int seg = (OUTMODE == 2) ? (n0 >> 11) : 0;
  unsigned short* outseg = (unsigned short*)Cout +
      (OUTMODE == 2 ? (size_t)seg * M * 2048 : 0);
  #pragma unroll
  for (int mf = 0; mf < 4; mf++) {
    const int row = rowl + mf * 16;
    #pragma unroll
    for (int nf = 0; nf < 4; nf++) {
      const int colb = coll + nf * 16;
      const float4 bv = *(const float4*)(bias + colb);
      float v0 = acc[mf][nf][0] + bv.x;
      float v1 = acc[mf][nf][1] + bv.y;
      float v2 = acc[mf][nf][2] + bv.z;
      float v3 = acc[mf][nf][3] + bv.w;
      if (OUTMODE == 2) {
        if (seg == 2) {
          v0 = tanhf_(v0); v1 = tanhf_(v1); v2 = tanhf_(v2); v3 = tanhf_(v3);
        } else {
          v0 = sigmoidf_(v0); v1 = sigmoidf_(v1); v2 = sigmoidf_(v2); v3 = sigmoidf_(v3);
        }
        uint2 pk = {pack2(v0, v1), pack2(v2, v3)};
        *(uint2*)(outseg + (size_t)row * 2048 + (colb & 2047)) = pk;
      } else if (OUTMODE == 1) {
        const size_t idx = (size_t)row * N + colb;
        const float4 rv = *(const float4*)(resid + idx);
        float4 ov = {v0 + rv.x, v1 + rv.y, v2 + rv.z, v3 + rv.w};
        *(float4*)((float*)Cout + idx) = ov;
      } else {
        uint2 pk = {pack2(v0, v1), pack2(v2, v3)};
        *(uint2*)((unsigned short*)Cout + (size_t)row * N + colb) = pk;
      }
    }
  }
}

// ---------------------------------------------------------------------------
// Causal depthwise conv (K=3) + SiLU + gate.  proj bf16 [B*S][2*INNER].
// ---------------------------------------------------------------------------
__global__ __launch_bounds__(256) void conv_gate_kernel(
    const unsigned short* __restrict__ proj, const float* __restrict__ conv_w,
    const float* __restrict__ conv_b, unsigned short* __restrict__ u) {
  const size_t idx = ((size_t)blockIdx.x * 256 + threadIdx.x) * 8;
  const int d = (int)(idx & (INNER - 1));
  const size_t bt = idx >> 11;
  const int t = (int)(bt & (SS - 1));
  const size_t rowbase = bt * (2 * INNER);
  const ushort8 zero = {0, 0, 0, 0, 0, 0, 0, 0};
  ushort8 p0 = *(const ushort8*)(proj + rowbase + d);
  ushort8 p1 = zero, p2 = zero;
  if (t >= 1) p1 = *(const ushort8*)(proj + rowbase - 2 * INNER + d);
  if (t >= 2) p2 = *(const ushort8*)(proj + rowbase - 4 * INNER + d);
  ushort8 g = *(const ushort8*)(proj + rowbase + INNER + d);
  ushort8 res;
  #pragma unroll
  for (int j = 0; j < 8; j++) {
    const int dj = d + j;
    float sv = conv_b[dj] + conv_w[dj * 3] * b2f(p2[j]) +
               conv_w[dj * 3 + 1] * b2f(p1[j]) + conv_w[dj * 3 + 2] * b2f(p0[j]);
    float uu = sv * sigmoidf_(sv) * sigmoidf_(b2f(g[j]));
    res[j] = f2b(uu);
  }
  *(ushort8*)(u + idx) = res;
}

// ---------------------------------------------------------------------------
// Chunked parallel scan, 3 phases.
// ---------------------------------------------------------------------------
__global__ __launch_bounds__(256) void scan_phase1(
    const unsigned short* __restrict__ a, const unsigned short* __restrict__ b,
    const unsigned short* __restrict__ u,
    float* __restrict__ P, float* __restrict__ S) {
  const int g = blockIdx.x * 256 + threadIdx.x;   // 65536 threads
  const int ch = (g & (INNER / 4 - 1)) * 4;
  const int chunk = (g >> 9) & (NCHK - 1);
  const int bb = g >> 14;
  size_t base = ((size_t)bb * SS + (size_t)chunk * CHUNK) * INNER + ch;
  float st0 = 0.f, st1 = 0.f, st2 = 0.f, st3 = 0.f;
  float p0 = 1.f, p1 = 1.f, p2 = 1.f, p3 = 1.f;
  for (int t = 0; t < CHUNK; t++) {
    const ushort4v av = *(const ushort4v*)(a + base);
    const ushort4v bv = *(const ushort4v*)(b + base);
    const ushort4v uv = *(const ushort4v*)(u + base);
    const float a0 = b2f(av[0]), a1 = b2f(av[1]), a2 = b2f(av[2]), a3 = b2f(av[3]);
    st0 = fmaf(a0, st0, b2f(bv[0]) * b2f(uv[0])); p0 *= a0;
    st1 = fmaf(a1, st1, b2f(bv[1]) * b2f(uv[1])); p1 *= a1;
    st2 = fmaf(a2, st2, b2f(bv[2]) * b2f(uv[2])); p2 *= a2;
    st3 = fmaf(a3, st3, b2f(bv[3]) * b2f(uv[3])); p3 *= a3;
    base += INNER;
  }
  const size_t o = ((size_t)bb * NCHK + chunk) * INNER + ch;
  *(float4*)(P + o) = (float4){p0, p1, p2, p3};
  *(float4*)(S + o) = (float4){st0, st1, st2, st3};
}

__global__ __launch_bounds__(256) void scan_phase2(
    const float* __restrict__ P, const float* __restrict__ S,
    float* __restrict__ Carry) {
  const int g = blockIdx.x * 256 + threadIdx.x;   // 8192 threads
  const int ch = g & (INNER - 1);
  const int bb = g >> 11;
  float carry = 0.f;
  for (int k = 0; k < NCHK; k++) {
    const size_t o = ((size_t)bb * NCHK + k) * INNER + ch;
    Carry[o] = carry;
    carry = fmaf(P[o], carry, S[o]);
  }
}

__global__ __launch_bounds__(256) void scan_phase3(
    const unsigned short* __restrict__ a, const unsigned short* __restrict__ b,
    const unsigned short* __restrict__ c, unsigned short* __restrict__ u,
    const float* __restrict__ Carry) {
  const int g = blockIdx.x * 256 + threadIdx.x;   // 65536 threads
  const int ch = (g & (INNER / 4 - 1)) * 4;
  const int chunk = (g >> 9) & (NCHK - 1);
  const int bb = g >> 14;
  size_t base = ((size_t)bb * SS + (size_t)chunk * CHUNK) * INNER + ch;
  const size_t o = ((size_t)bb * NCHK + chunk) * INNER + ch;
  const float4 cv = *(const float4*)(Carry + o);
  float st0 = cv.x, st1 = cv.y, st2 = cv.z, st3 = cv.w;
  for (int t = 0; t < CHUNK; t++) {
    const ushort4v av = *(const ushort4v*)(a + base);
    const ushort4v bv = *(const ushort4v*)(b + base);
    const ushort4v ccv = *(const ushort4v*)(c + base);
    const ushort4v uv = *(const ushort4v*)(u + base);
    const float u0 = b2f(uv[0]), u1 = b2f(uv[1]), u2 = b2f(uv[2]), u3 = b2f(uv[3]);
    st0 = fmaf(b2f(av[0]), st0, b2f(bv[0]) * u0);
    st1 = fmaf(b2f(av[1]), st1, b2f(bv[1]) * u1);
    st2 = fmaf(b2f(av[2]), st2, b2f(bv[2]) * u2);
    st3 = fmaf(b2f(av[3]), st3, b2f(bv[3]) * u3);
    ushort4v yv;
    yv[0] = f2b(fmaf(b2f(ccv[0]), st0, u0));
    yv[1] = f2b(fmaf(b2f(ccv[1]), st1, u1));
    yv[2] = f2b(fmaf(b2f(ccv[2]), st2, u2));
    yv[3] = f2b(fmaf(b2f(ccv[3]), st3, u3));
    *(ushort4v*)(u + base) = yv;
    base += INNER;
  }
}

// ---------------------------------------------------------------------------
extern "C" void kernel_launch(void* const* d_in, const int* in_sizes, int n_in,
                              void* d_out, int out_size, void* d_ws, size_t ws_size,
                              hipStream_t stream) {
  const float* x      = (const float*)d_in[0];
  const float* W_in   = (const float*)d_in[1];
  const float* b_in   = (const float*)d_in[2];
  const float* conv_w = (const float*)d_in[3];
  const float* conv_b = (const float*)d_in[4];
  const float* Wa     = (const float*)d_in[5];
  const float* ba     = (const float*)d_in[6];
  const float* Wb     = (const float*)d_in[7];
  const float* b_b    = (const float*)d_in[8];
  const float* Wc     = (const float*)d_in[9];
  const float* bc     = (const float*)d_in[10];
  const float* Wo     = (const float*)d_in[11];
  const float* bo     = (const float*)d_in[12];
  const float* gamma  = (const float*)d_in[13];
  const float* beta   = (const float*)d_in[14];
  float* out = (float*)d_out;

  const size_t M = (size_t)BB * SS;  // 8192
  char* ws = (char*)d_ws;
  size_t off = 0;
  auto alloc = [&](size_t bytes) {
    char* p = ws + off;
    off += (bytes + 255) & ~(size_t)255;
    return p;
  };
  unsigned short* WinT  = (unsigned short*)alloc((size_t)4096 * 1024 * 2);  // 8 MB
  unsigned short* WabcT = (unsigned short*)alloc((size_t)6144 * 2048 * 2);  // 24 MB
  unsigned short* WoT   = (unsigned short*)alloc((size_t)1024 * 2048 * 2);  // 4 MB
  float*          biasABC = (float*)alloc(6144 * 4);
  unsigned short* xnB   = (unsigned short*)alloc(M * DM * 2);               // 16 MB
  unsigned short* uB    = (unsigned short*)alloc(M * INNER * 2);            // 32 MB
  unsigned short* abc   = (unsigned short*)alloc(3 * M * INNER * 2);        // 96 MB
  unsigned short* proj = abc;
  unsigned short* aB = abc;
  unsigned short* bB = abc + M * INNER;
  unsigned short* cB = abc + 2 * M * INNER;
  float* Pbuf  = (float*)xnB;          // xnB dead after proj GEMM
  float* Sbuf  = Pbuf + (size_t)BB * NCHK * INNER;
  float* Carry = Sbuf + (size_t)BB * NCHK * INNER;

  hipMemcpyAsync(biasABC,        ba,  2048 * 4, hipMemcpyDeviceToDevice, stream);
  hipMemcpyAsync(biasABC + 2048, b_b, 2048 * 4, hipMemcpyDeviceToDevice, stream);
  hipMemcpyAsync(biasABC + 4096, bc,  2048 * 4, hipMemcpyDeviceToDevice, stream);

  const dim3 tb(32, 8);
  transpose_cast_kernel<<<dim3(128, 32), tb, 0, stream>>>(W_in, WinT, 1024, 4096);
  transpose_cast_kernel<<<dim3(64, 64), tb, 0, stream>>>(Wa, WabcT, 2048, 2048);
  transpose_cast_kernel<<<dim3(64, 64), tb, 0, stream>>>(Wb, WabcT + 2048 * 2048, 2048, 2048);
  transpose_cast_kernel<<<dim3(64, 64), tb, 0, stream>>>(Wc, WabcT + 2 * 2048 * 2048, 2048, 2048);
  transpose_cast_kernel<<<dim3(32, 64), tb, 0, stream>>>(Wo, WoT, 2048, 1024);

  layernorm_kernel<<<M, 256, 0, stream>>>(x, gamma, beta, xnB);

  // proj = xn @ W_in + b_in            [8192 x 4096], grid 32x32 = 1024
  gemm_mn<0><<<dim3(1024), 512, 0, stream>>>(
      xnB, WinT, b_in, proj, nullptr, M, 4096, 1024, 32);

  // u = silu(conv(projected)) * sigmoid(gate)
  conv_gate_kernel<<<(M * INNER) / (256 * 8), 256, 0, stream>>>(proj, conv_w, conv_b, uB);

  // a,b,c fused: [8192 x 6144], grid 32x48 = 1536
  gemm_mn<2><<<dim3(1536), 512, 0, stream>>>(
      uB, WabcT, biasABC, abc, nullptr, M, 6144, 2048, 48);

  // chunked scan (y overwrites u)
  scan_phase1<<<256, 256, 0, stream>>>(aB, bB, uB, Pbuf, Sbuf);
  scan_phase2<<<32, 256, 0, stream>>>(Pbuf, Sbuf, Carry);
  scan_phase3<<<256, 256, 0, stream>>>(aB, bB, cB, uB, Carry);

  // out = x + y @ Wo + bo              [8192 x 1024] fp32, grid 32x8 = 256
  gemm_mn<1><<<dim3(256), 512, 0, stream>>>(
      uB, WoT, bo, out, x, M, 1024, 2048, 8);
}

// Round 7
// 517.189 us; speedup vs baseline: 1.1785x; 1.1785x over previous
//
#include <hip/hip_runtime.h>
#include <hip/hip_bf16.h>
#include <cstdint>
#include <cstddef>

#define BB 4
#define SS 2048
#define DM 1024
#define INNER 2048
#define CHUNK 64
#define NCHK (SS / CHUNK)  // 32

typedef __attribute__((ext_vector_type(8))) __bf16 bf16x8;
typedef __attribute__((ext_vector_type(4))) float f32x4;
typedef __attribute__((ext_vector_type(8))) unsigned short ushort8;
typedef __attribute__((ext_vector_type(4))) unsigned short ushort4v;

#define GPTR(p) ((const __attribute__((address_space(1))) void*)(p))
#define LPTR(p) ((__attribute__((address_space(3))) void*)(p))
#define SB() __builtin_amdgcn_sched_barrier(0)

__device__ inline float b2f(unsigned short h) {
  union { unsigned u; float f; } v; v.u = ((unsigned)h) << 16; return v.f;
}
__device__ inline unsigned short f2b(float f) {
  unsigned u = __float_as_uint(f);
  u += 0x7fff + ((u >> 16) & 1);   // round-to-nearest-even
  return (unsigned short)(u >> 16);
}
__device__ inline unsigned pack2(float lo, float hi) {
  return (unsigned)f2b(lo) | ((unsigned)f2b(hi) << 16);
}
__device__ inline float sigmoidf_(float x) { return 1.0f / (1.0f + __expf(-x)); }
__device__ inline float tanhf_(float x) { return 2.0f / (1.0f + __expf(-2.0f * x)) - 1.0f; }

// ---------------------------------------------------------------------------
// Transpose + cast: src fp32 [R][C] -> dst bf16 [C][R]
// ---------------------------------------------------------------------------
__global__ void transpose_cast_kernel(const float* __restrict__ src,
                                      unsigned short* __restrict__ dst,
                                      int R, int C) {
  __shared__ float tile[32][33];
  const int c0 = blockIdx.x * 32, r0 = blockIdx.y * 32;
  const int tx = threadIdx.x, ty = threadIdx.y;  // (32,8)
  #pragma unroll
  for (int j = ty; j < 32; j += 8)
    tile[j][tx] = src[(size_t)(r0 + j) * C + c0 + tx];
  __syncthreads();
  #pragma unroll
  for (int j = ty; j < 32; j += 8)
    dst[(size_t)(c0 + j) * R + r0 + tx] = f2b(tile[tx][j]);
}

// ---------------------------------------------------------------------------
// LayerNorm: x fp32 [8192][1024] -> xn bf16
// ---------------------------------------------------------------------------
__global__ __launch_bounds__(256) void layernorm_kernel(
    const float* __restrict__ x, const float* __restrict__ gamma,
    const float* __restrict__ beta, unsigned short* __restrict__ out) {
  const int row = blockIdx.x;
  const int tid = threadIdx.x;
  const float4 v = *(const float4*)(x + (size_t)row * DM + tid * 4);
  float s = v.x + v.y + v.z + v.w;
  #pragma unroll
  for (int o = 32; o >= 1; o >>= 1) s += __shfl_down(s, o, 64);
  __shared__ float red[8];
  const int wid = tid >> 6, lane = tid & 63;
  if (lane == 0) red[wid] = s;
  __syncthreads();
  const float mu = (red[0] + red[1] + red[2] + red[3]) * (1.f / DM);
  const float d0 = v.x - mu, d1 = v.y - mu, d2 = v.z - mu, d3 = v.w - mu;
  float sq = d0 * d0 + d1 * d1 + d2 * d2 + d3 * d3;
  #pragma unroll
  for (int o = 32; o >= 1; o >>= 1) sq += __shfl_down(sq, o, 64);
  if (lane == 0) red[4 + wid] = sq;
  __syncthreads();
  const float var = (red[4] + red[5] + red[6] + red[7]) * (1.f / DM);
  const float rs = rsqrtf(var + 1e-5f);
  const int c0 = tid * 4;
  ushort4v o4;
  o4[0] = f2b(d0 * rs * gamma[c0 + 0] + beta[c0 + 0]);
  o4[1] = f2b(d1 * rs * gamma[c0 + 1] + beta[c0 + 1]);
  o4[2] = f2b(d2 * rs * gamma[c0 + 2] + beta[c0 + 2]);
  o4[3] = f2b(d3 * rs * gamma[c0 + 3] + beta[c0 + 3]);
  *(ushort4v*)(out + (size_t)row * DM + c0) = o4;
}

// ---------------------------------------------------------------------------
// 256x256 GEMM, BK=64, 512 threads (8 waves, 2Mx4N, wave tile 128x64).
// m201-style 4-phase fine-interleaved schedule per K-tile:
//   P1: stage A-halves(t+1) | vmcnt(4)+bar | 8 ds_reads | 16 MFMA | bar
//   P2: stage B-halves(t+1) |               4 ds_reads  | 16 MFMA | bar
//   P3:                                     8 ds_reads  | 16 MFMA | bar
//   P4:                                     4 ds_reads  | 16 MFMA | bar
// Counted vmcnt (never drains in loop); 2x64KB LDS double buffer.
// LDS layout (per region, elems): (row>>4)*1024 + (k>>3)*128 + (row&15)*8
//   -> each 16-lane group of a ds_read_b128 is 256B-contiguous: conflict-free
//   -> staging: linear LDS dest (unit=thread), per-lane permuted GLOBAL src.
// Operand-swapped MFMA: acc = mfma(B, A, acc) -> lane holds 4 consecutive C
// columns -> packed stores.
// OUTMODE 0: bf16. OUTMODE 2: abc-fused (seg0/1 sigmoid, seg2 tanh).
// ---------------------------------------------------------------------------
template <int OUTMODE>
__global__ __launch_bounds__(512, 1) void gemm64(
    const unsigned short* __restrict__ A, const unsigned short* __restrict__ Bt,
    const float* __restrict__ bias, void* __restrict__ Cout,
    int M, int N, int K, int nbx) {
  __shared__ unsigned short lds[2 * 32768];  // 128 KB
  const int tid = threadIdx.x;
  // bijective XCD swizzle (gridDim.x % 8 == 0)
  const int nwg = gridDim.x;
  const int cpx = nwg >> 3;
  const int bid = blockIdx.x;
  const int swz = (bid & 7) * cpx + (bid >> 3);
  const int m0 = (swz / nbx) * 256, n0 = (swz % nbx) * 256;

  const int l = tid & 63, w = tid >> 6;
  const int wr = w >> 2, wc = w & 3;          // 2(M) x 4(N) wave grid
  const int NT = K >> 6;                      // K-tiles of 64

  // fragment base offsets (elems), kk adds 512, mf/nf add 1024
  const int a_off = (wr * 8) * 1024 + (l >> 4) * 128 + (l & 15) * 8;
  const int b_off = 16384 + (wc * 4) * 1024 + (l >> 4) * 128 + (l & 15) * 8;

  f32x4 acc[8][4];
  #pragma unroll
  for (int i = 0; i < 8; i++)
    #pragma unroll
    for (int j = 0; j < 4; j++) acc[i][j] = (f32x4){0.f, 0.f, 0.f, 0.f};

  // staging: unit u (16B) holds row=((u>>7)<<4)|(u&15), kslot=(u>>4)&7.
  // thread covers units {h*1024+tid, h*1024+512+tid} per half h.
  const int r0 = ((tid >> 7) << 4) | (tid & 15);
  const int s0 = (tid >> 4) & 7;
  const unsigned short* Abase = A + (size_t)(m0 + r0) * K + s0 * 8;
  const unsigned short* Bbase = Bt + (size_t)(n0 + r0) * K + s0 * 8;
  const size_t rs64 = (size_t)64 * K;

  auto stageA = [&](int kt, int h) {
    int ktw = kt; if (ktw >= NT) ktw -= NT;
    const int k0 = ktw << 6;
    const int bo = (kt & 1) * 32768 + h * 8192 + tid * 8;
    const unsigned short* src = Abase + (size_t)(h * 128) * K + k0;
    __builtin_amdgcn_global_load_lds(GPTR(src), LPTR(&lds[bo]), 16, 0, 0);
    __builtin_amdgcn_global_load_lds(GPTR(src + rs64), LPTR(&lds[bo + 4096]), 16, 0, 0);
  };
  auto stageB = [&](int kt, int h) {
    int ktw = kt; if (ktw >= NT) ktw -= NT;
    const int k0 = ktw << 6;
    const int bo = (kt & 1) * 32768 + 16384 + h * 8192 + tid * 8;
    const unsigned short* src = Bbase + (size_t)(h * 128) * K + k0;
    __builtin_amdgcn_global_load_lds(GPTR(src), LPTR(&lds[bo]), 16, 0, 0);
    __builtin_amdgcn_global_load_lds(GPTR(src + rs64), LPTR(&lds[bo + 4096]), 16, 0, 0);
  };

  // prologue: tile 0 fully staged (8 loads outstanding)
  stageA(0, 0); stageA(0, 1); stageB(0, 0); stageB(0, 1);

  for (int t = 0; t < NT; t++) {
    const int tbo = (t & 1) * 32768;
    bf16x8 af[4], bf[4], ag[4];

    // ===== P1: stage A(t+1); tile t resident; kk0, mf0-3 =====
    stageA(t + 1, 0); stageA(t + 1, 1);
    SB();
    asm volatile("s_waitcnt vmcnt(4)" ::: "memory");
    SB();
    __builtin_amdgcn_s_barrier();
    SB();
    #pragma unroll
    for (int nf = 0; nf < 4; nf++)
      bf[nf] = *(const bf16x8*)&lds[tbo + b_off + nf * 1024];
    #pragma unroll
    for (int mf = 0; mf < 4; mf++)
      af[mf] = *(const bf16x8*)&lds[tbo + a_off + mf * 1024];
    asm volatile("s_waitcnt lgkmcnt(0)" ::: "memory");
    SB();
    __builtin_amdgcn_s_setprio(1);
    #pragma unroll
    for (int mf = 0; mf < 4; mf++)
      #pragma unroll
      for (int nf = 0; nf < 4; nf++)
        acc[mf][nf] = __builtin_amdgcn_mfma_f32_16x16x32_bf16(bf[nf], af[mf], acc[mf][nf], 0, 0, 0);
    __builtin_amdgcn_s_setprio(0);
    SB();
    __builtin_amdgcn_s_barrier();
    SB();

    // ===== P2: stage B(t+1); kk0, mf4-7 =====
    stageB(t + 1, 0); stageB(t + 1, 1);
    SB();
    #pragma unroll
    for (int mf = 0; mf < 4; mf++)
      ag[mf] = *(const bf16x8*)&lds[tbo + a_off + (4 + mf) * 1024];
    asm volatile("s_waitcnt lgkmcnt(0)" ::: "memory");
    SB();
    __builtin_amdgcn_s_setprio(1);
    #pragma unroll
    for (int mf = 0; mf < 4; mf++)
      #pragma unroll
      for (int nf = 0; nf < 4; nf++)
        acc[4 + mf][nf] = __builtin_amdgcn_mfma_f32_16x16x32_bf16(bf[nf], ag[mf], acc[4 + mf][nf], 0, 0, 0);
    __builtin_amdgcn_s_setprio(0);
    SB();
    __builtin_amdgcn_s_barrier();
    SB();

    // ===== P3: kk1, mf0-3 =====
    #pragma unroll
    for (int nf = 0; nf < 4; nf++)
      bf[nf] = *(const bf16x8*)&lds[tbo + b_off + nf * 1024 + 512];
    #pragma unroll
    for (int mf = 0; mf < 4; mf++)
      af[mf] = *(const bf16x8*)&lds[tbo + a_off + mf * 1024 + 512];
    asm volatile("s_waitcnt lgkmcnt(0)" ::: "memory");
    SB();
    __builtin_amdgcn_s_setprio(1);
    #pragma unroll
    for (int mf = 0; mf < 4; mf++)
      #pragma unroll
      for (int nf = 0; nf < 4; nf++)
        acc[mf][nf] = __builtin_amdgcn_mfma_f32_16x16x32_bf16(bf[nf], af[mf], acc[mf][nf], 0, 0, 0);
    __builtin_amdgcn_s_setprio(0);
    SB();
    __builtin_amdgcn_s_barrier();
    SB();

    // ===== P4: kk1, mf4-7 =====
    #pragma unroll
    for (int mf = 0; mf < 4; mf++)
      ag[mf] = *(const bf16x8*)&lds[tbo + a_off + (4 + mf) * 1024 + 512];
    asm volatile("s_waitcnt lgkmcnt(0)" ::: "memory");
    SB();
    __builtin_amdgcn_s_setprio(1);
    #pragma unroll
    for (int mf = 0; mf < 4; mf++)
      #pragma unroll
      for (int nf = 0; nf < 4; nf++)
        acc[4 + mf][nf] = __builtin_amdgcn_mfma_f32_16x16x32_bf16(bf[nf], ag[mf], acc[4 + mf][nf], 0, 0, 0);
    __builtin_amdgcn_s_setprio(0);
    SB();
    __builtin_amdgcn_s_barrier();
    SB();
  }
  asm volatile("s_waitcnt vmcnt(0)" ::: "memory");

  // epilogue: lane holds C[row][colb..colb+3]
  const int rowl = m0 + wr * 128 + (l & 15);
  const int coll = n0 + wc * 64 + (l >> 4) * 4;
  const int seg = (OUTMODE == 2) ? (n0 >> 11) : 0;
  unsigned short* outseg = (unsigned short*)Cout +
      (OUTMODE == 2 ? (size_t)seg * M * 2048 : 0);
  #pragma unroll
  for (int mf = 0; mf < 8; mf++) {
    const int row = rowl + mf * 16;
    #pragma unroll
    for (int nf = 0; nf < 4; nf++) {
      const int colb = coll + nf * 16;
      const float4 bv = *(const float4*)(bias + colb);
      float v0 = acc[mf][nf][0] + bv.x;
      float v1 = acc[mf][nf][1] + bv.y;
      float v2 = acc[mf][nf][2] + bv.z;
      float v3 = acc[mf][nf][3] + bv.w;
      if (OUTMODE == 2) {
        if (seg == 2) {
          v0 = tanhf_(v0); v1 = tanhf_(v1); v2 = tanhf_(v2); v3 = tanhf_(v3);
        } else {
          v0 = sigmoidf_(v0); v1 = sigmoidf_(v1); v2 = sigmoidf_(v2); v3 = sigmoidf_(v3);
        }
        uint2 pk = {pack2(v0, v1), pack2(v2, v3)};
        *(uint2*)(outseg + (size_t)row * 2048 + (colb & 2047)) = pk;
      } else {
        uint2 pk = {pack2(v0, v1), pack2(v2, v3)};
        *(uint2*)((unsigned short*)Cout + (size_t)row * N + colb) = pk;
      }
    }
  }
}

// ---------------------------------------------------------------------------
// 128x128 GEMM (old structure) — kept for the Wo GEMM (N=1024 grid shape).
// OUTMODE 1: fp32 + residual.
// ---------------------------------------------------------------------------
template <int ACT, int OUTMODE>
__global__ __launch_bounds__(256) void gemm_bt(
    const unsigned short* __restrict__ A, const unsigned short* __restrict__ Bt,
    const float* __restrict__ bias, void* __restrict__ Cout,
    const float* __restrict__ resid, int M, int N, int K) {
  __shared__ unsigned short Alds[128 * 32];
  __shared__ unsigned short Blds[128 * 32];
  const int tid = threadIdx.x;
  const int m0 = blockIdx.y * 128, n0 = blockIdx.x * 128;
  const int l = tid & 63, w = tid >> 6;
  const int wr = w >> 1, wc = w & 1;

  f32x4 acc[4][4];
  #pragma unroll
  for (int i = 0; i < 4; i++)
    #pragma unroll
    for (int j = 0; j < 4; j++) acc[i][j] = (f32x4){0.f, 0.f, 0.f, 0.f};

  const int c0 = tid, c1 = tid + 256;
  const unsigned short* Ag0 = A + (size_t)(m0 + (c0 >> 2)) * K + (c0 & 3) * 8;
  const unsigned short* Ag1 = A + (size_t)(m0 + (c1 >> 2)) * K + (c1 & 3) * 8;
  const unsigned short* Bg0 = Bt + (size_t)(n0 + (c0 >> 2)) * K + (c0 & 3) * 8;
  const unsigned short* Bg1 = Bt + (size_t)(n0 + (c1 >> 2)) * K + (c1 & 3) * 8;
  const int frag_off = (l & 15) * 32 + (l >> 4) * 8;

  for (int k0 = 0; k0 < K; k0 += 32) {
    __builtin_amdgcn_global_load_lds(GPTR(Ag0 + k0), LPTR(&Alds[c0 * 8]), 16, 0, 0);
    __builtin_amdgcn_global_load_lds(GPTR(Ag1 + k0), LPTR(&Alds[c1 * 8]), 16, 0, 0);
    __builtin_amdgcn_global_load_lds(GPTR(Bg0 + k0), LPTR(&Blds[c0 * 8]), 16, 0, 0);
    __builtin_amdgcn_global_load_lds(GPTR(Bg1 + k0), LPTR(&Blds[c1 * 8]), 16, 0, 0);
    __syncthreads();
    bf16x8 af[4], bfv[4];
    #pragma unroll
    for (int m = 0; m < 4; m++)
      af[m] = *(const bf16x8*)(&Alds[(wr * 64 + m * 16) * 32 + frag_off]);
    #pragma unroll
    for (int n = 0; n < 4; n++)
      bfv[n] = *(const bf16x8*)(&Blds[(wc * 64 + n * 16) * 32 + frag_off]);
    #pragma unroll
    for (int m = 0; m < 4; m++)
      #pragma unroll
      for (int n = 0; n < 4; n++)
        acc[m][n] = __builtin_amdgcn_mfma_f32_16x16x32_bf16(af[m], bfv[n], acc[m][n], 0, 0, 0);
    __syncthreads();
  }

  #pragma unroll
  for (int n = 0; n < 4; n++) {
    const int col = n0 + wc * 64 + n * 16 + (l & 15);
    const float bv = bias[col];
    #pragma unroll
    for (int m = 0; m < 4; m++) {
      const int rowb = m0 + wr * 64 + m * 16 + (l >> 4) * 4;
      #pragma unroll
      for (int r = 0; r < 4; r++) {
        float v = acc[m][n][r] + bv;
        if (ACT == 1) v = sigmoidf_(v);
        else if (ACT == 2) v = tanhf_(v);
        const size_t idx = (size_t)(rowb + r) * N + col;
        if (OUTMODE == 0) ((unsigned short*)Cout)[idx] = f2b(v);
        else ((float*)Cout)[idx] = v + resid[idx];
      }
    }
  }
}

// ---------------------------------------------------------------------------
// Causal depthwise conv (K=3) + SiLU + gate.  proj bf16 [B*S][2*INNER].
// ---------------------------------------------------------------------------
__global__ __launch_bounds__(256) void conv_gate_kernel(
    const unsigned short* __restrict__ proj, const float* __restrict__ conv_w,
    const float* __restrict__ conv_b, unsigned short* __restrict__ u) {
  const size_t idx = ((size_t)blockIdx.x * 256 + threadIdx.x) * 8;
  const int d = (int)(idx & (INNER - 1));
  const size_t bt = idx >> 11;
  const int t = (int)(bt & (SS - 1));
  const size_t rowbase = bt * (2 * INNER);
  const ushort8 zero = {0, 0, 0, 0, 0, 0, 0, 0};
  ushort8 p0 = *(const ushort8*)(proj + rowbase + d);
  ushort8 p1 = zero, p2 = zero;
  if (t >= 1) p1 = *(const ushort8*)(proj + rowbase - 2 * INNER + d);
  if (t >= 2) p2 = *(const ushort8*)(proj + rowbase - 4 * INNER + d);
  ushort8 g = *(const ushort8*)(proj + rowbase + INNER + d);
  ushort8 res;
  #pragma unroll
  for (int j = 0; j < 8; j++) {
    const int dj = d + j;
    float sv = conv_b[dj] + conv_w[dj * 3] * b2f(p2[j]) +
               conv_w[dj * 3 + 1] * b2f(p1[j]) + conv_w[dj * 3 + 2] * b2f(p0[j]);
    float uu = sv * sigmoidf_(sv) * sigmoidf_(b2f(g[j]));
    res[j] = f2b(uu);
  }
  *(ushort8*)(u + idx) = res;
}

// ---------------------------------------------------------------------------
// Chunked parallel scan, 3 phases.
// ---------------------------------------------------------------------------
__global__ __launch_bounds__(256) void scan_phase1(
    const unsigned short* __restrict__ a, const unsigned short* __restrict__ b,
    const unsigned short* __restrict__ u,
    float* __restrict__ P, float* __restrict__ S) {
  const int g = blockIdx.x * 256 + threadIdx.x;   // 65536 threads
  const int ch = (g & (INNER / 4 - 1)) * 4;
  const int chunk = (g >> 9) & (NCHK - 1);
  const int bb = g >> 14;
  size_t base = ((size_t)bb * SS + (size_t)chunk * CHUNK) * INNER + ch;
  float st0 = 0.f, st1 = 0.f, st2 = 0.f, st3 = 0.f;
  float p0 = 1.f, p1 = 1.f, p2 = 1.f, p3 = 1.f;
  for (int t = 0; t < CHUNK; t++) {
    const ushort4v av = *(const ushort4v*)(a + base);
    const ushort4v bv = *(const ushort4v*)(b + base);
    const ushort4v uv = *(const ushort4v*)(u + base);
    const float a0 = b2f(av[0]), a1 = b2f(av[1]), a2 = b2f(av[2]), a3 = b2f(av[3]);
    st0 = fmaf(a0, st0, b2f(bv[0]) * b2f(uv[0])); p0 *= a0;
    st1 = fmaf(a1, st1, b2f(bv[1]) * b2f(uv[1])); p1 *= a1;
    st2 = fmaf(a2, st2, b2f(bv[2]) * b2f(uv[2])); p2 *= a2;
    st3 = fmaf(a3, st3, b2f(bv[3]) * b2f(uv[3])); p3 *= a3;
    base += INNER;
  }
  const size_t o = ((size_t)bb * NCHK + chunk) * INNER + ch;
  *(float4*)(P + o) = (float4){p0, p1, p2, p3};
  *(float4*)(S + o) = (float4){st0, st1, st2, st3};
}

__global__ __launch_bounds__(256) void scan_phase2(
    const float* __restrict__ P, const float* __restrict__ S,
    float* __restrict__ Carry) {
  const int g = blockIdx.x * 256 + threadIdx.x;   // 8192 threads
  const int ch = g & (INNER - 1);
  const int bb = g >> 11;
  float carry = 0.f;
  for (int k = 0; k < NCHK; k++) {
    const size_t o = ((size_t)bb * NCHK + k) * INNER + ch;
    Carry[o] = carry;
    carry = fmaf(P[o], carry, S[o]);
  }
}

__global__ __launch_bounds__(256) void scan_phase3(
    const unsigned short* __restrict__ a, const unsigned short* __restrict__ b,
    const unsigned short* __restrict__ c, unsigned short* __restrict__ u,
    const float* __restrict__ Carry) {
  const int g = blockIdx.x * 256 + threadIdx.x;   // 65536 threads
  const int ch = (g & (INNER / 4 - 1)) * 4;
  const int chunk = (g >> 9) & (NCHK - 1);
  const int bb = g >> 14;
  size_t base = ((size_t)bb * SS + (size_t)chunk * CHUNK) * INNER + ch;
  const size_t o = ((size_t)bb * NCHK + chunk) * INNER + ch;
  const float4 cv = *(const float4*)(Carry + o);
  float st0 = cv.x, st1 = cv.y, st2 = cv.z, st3 = cv.w;
  for (int t = 0; t < CHUNK; t++) {
    const ushort4v av = *(const ushort4v*)(a + base);
    const ushort4v bv = *(const ushort4v*)(b + base);
    const ushort4v ccv = *(const ushort4v*)(c + base);
    const ushort4v uv = *(const ushort4v*)(u + base);
    const float u0 = b2f(uv[0]), u1 = b2f(uv[1]), u2 = b2f(uv[2]), u3 = b2f(uv[3]);
    st0 = fmaf(b2f(av[0]), st0, b2f(bv[0]) * u0);
    st1 = fmaf(b2f(av[1]), st1, b2f(bv[1]) * u1);
    st2 = fmaf(b2f(av[2]), st2, b2f(bv[2]) * u2);
    st3 = fmaf(b2f(av[3]), st3, b2f(bv[3]) * u3);
    ushort4v yv;
    yv[0] = f2b(fmaf(b2f(ccv[0]), st0, u0));
    yv[1] = f2b(fmaf(b2f(ccv[1]), st1, u1));
    yv[2] = f2b(fmaf(b2f(ccv[2]), st2, u2));
    yv[3] = f2b(fmaf(b2f(ccv[3]), st3, u3));
    *(ushort4v*)(u + base) = yv;
    base += INNER;
  }
}

// ---------------------------------------------------------------------------
extern "C" void kernel_launch(void* const* d_in, const int* in_sizes, int n_in,
                              void* d_out, int out_size, void* d_ws, size_t ws_size,
                              hipStream_t stream) {
  const float* x      = (const float*)d_in[0];
  const float* W_in   = (const float*)d_in[1];
  const float* b_in   = (const float*)d_in[2];
  const float* conv_w = (const float*)d_in[3];
  const float* conv_b = (const float*)d_in[4];
  const float* Wa     = (const float*)d_in[5];
  const float* ba     = (const float*)d_in[6];
  const float* Wb     = (const float*)d_in[7];
  const float* b_b    = (const float*)d_in[8];
  const float* Wc     = (const float*)d_in[9];
  const float* bc     = (const float*)d_in[10];
  const float* Wo     = (const float*)d_in[11];
  const float* bo     = (const float*)d_in[12];
  const float* gamma  = (const float*)d_in[13];
  const float* beta   = (const float*)d_in[14];
  float* out = (float*)d_out;

  const size_t M = (size_t)BB * SS;  // 8192
  char* ws = (char*)d_ws;
  size_t off = 0;
  auto alloc = [&](size_t bytes) {
    char* p = ws + off;
    off += (bytes + 255) & ~(size_t)255;
    return p;
  };
  unsigned short* WinT  = (unsigned short*)alloc((size_t)4096 * 1024 * 2);  // 8 MB
  unsigned short* WabcT = (unsigned short*)alloc((size_t)6144 * 2048 * 2);  // 24 MB
  unsigned short* WoT   = (unsigned short*)alloc((size_t)1024 * 2048 * 2);  // 4 MB
  float*          biasABC = (float*)alloc(6144 * 4);
  unsigned short* xnB   = (unsigned short*)alloc(M * DM * 2);               // 16 MB
  unsigned short* uB    = (unsigned short*)alloc(M * INNER * 2);            // 32 MB
  unsigned short* abc   = (unsigned short*)alloc(3 * M * INNER * 2);        // 96 MB
  unsigned short* proj = abc;
  unsigned short* aB = abc;
  unsigned short* bB = abc + M * INNER;
  unsigned short* cB = abc + 2 * M * INNER;
  float* Pbuf  = (float*)xnB;          // xnB dead after proj GEMM
  float* Sbuf  = Pbuf + (size_t)BB * NCHK * INNER;
  float* Carry = Sbuf + (size_t)BB * NCHK * INNER;

  hipMemcpyAsync(biasABC,        ba,  2048 * 4, hipMemcpyDeviceToDevice, stream);
  hipMemcpyAsync(biasABC + 2048, b_b, 2048 * 4, hipMemcpyDeviceToDevice, stream);
  hipMemcpyAsync(biasABC + 4096, bc,  2048 * 4, hipMemcpyDeviceToDevice, stream);

  const dim3 tb(32, 8);
  transpose_cast_kernel<<<dim3(128, 32), tb, 0, stream>>>(W_in, WinT, 1024, 4096);
  transpose_cast_kernel<<<dim3(64, 64), tb, 0, stream>>>(Wa, WabcT, 2048, 2048);
  transpose_cast_kernel<<<dim3(64, 64), tb, 0, stream>>>(Wb, WabcT + 2048 * 2048, 2048, 2048);
  transpose_cast_kernel<<<dim3(64, 64), tb, 0, stream>>>(Wc, WabcT + 2 * 2048 * 2048, 2048, 2048);
  transpose_cast_kernel<<<dim3(32, 64), tb, 0, stream>>>(Wo, WoT, 2048, 1024);

  layernorm_kernel<<<M, 256, 0, stream>>>(x, gamma, beta, xnB);

  // proj = xn @ W_in + b_in            [8192 x 4096], grid 16x32 = 512
  gemm64<0><<<dim3(512), 512, 0, stream>>>(
      xnB, WinT, b_in, proj, M, 4096, 1024, 16);

  // u = silu(conv(projected)) * sigmoid(gate)
  conv_gate_kernel<<<(M * INNER) / (256 * 8), 256, 0, stream>>>(proj, conv_w, conv_b, uB);

  // a,b,c fused: [8192 x 6144], grid 24x32 = 768
  gemm64<2><<<dim3(768), 512, 0, stream>>>(
      uB, WabcT, biasABC, abc, M, 6144, 2048, 24);

  // chunked scan (y overwrites u)
  scan_phase1<<<256, 256, 0, stream>>>(aB, bB, uB, Pbuf, Sbuf);
  scan_phase2<<<32, 256, 0, stream>>>(Pbuf, Sbuf, Carry);
  scan_phase3<<<256, 256, 0, stream>>>(aB, bB, cB, uB, Carry);

  // out = x + y @ Wo + bo              [8192 x 1024] fp32
  gemm_bt<0, 1><<<dim3(8, 64), 256, 0, stream>>>(
      uB, WoT, bo, out, x, M, 1024, 2048);
}